// Round 12
// baseline (566.461 us; speedup 1.0000x reference)
//
#include <hip/hip_runtime.h>
#include <stdint.h>

// alpha^(i-5) for i=0..15 (alpha=0.9); pw = alpha^d uses c_tab[d+5]
__device__ __constant__ float c_tab[16] = {
  1.6935087808430286f, 1.5241579027587256f, 1.3717421124828532f,
  1.2345679012345678f, 1.1111111111111112f, 1.0f, 0.9f, 0.81f,
  0.729f, 0.6561f, 0.59049f, 0.531441f, 0.4782969f, 0.43046721f,
  0.387420489f, 0.3486784401f };

__device__ __forceinline__ float bf2f(uint32_t u) {  // low 16 bits = bf16
  union { unsigned int i; float f; } v; v.i = u << 16; return v.f;
}
__device__ __forceinline__ uint16_t f2bf(float f) {
  union { float f; unsigned int i; } v; v.f = f;
  unsigned r = v.i + 0x7FFFu + ((v.i >> 16) & 1u);  // RNE
  return (uint16_t)(r >> 16);
}

// ---- mask dtype probe ----
__global__ void k_detect(const uint8_t* __restrict__ m, int nbytes,
                         int* __restrict__ flag) {
  int i = blockIdx.x * blockDim.x + threadIdx.x;
  if (i < nbytes && (i & 3) && m[i]) atomicOr(flag, 1);
}

// ---- build initial 64-bit reach masks straight from the raw mask ----
__global__ void k_init_masks(const uint8_t* __restrict__ raw,
                             const int* __restrict__ flag,
                             unsigned long long* __restrict__ R, int N) {
  int n = blockIdx.x * blockDim.x + threadIdx.x;
  if (n >= N) return;
  unsigned long long r = 0;
  if (*flag) {  // u8/bool wire format
    const unsigned long long* m8 =
        (const unsigned long long*)(raw + (size_t)n * 64);
#pragma unroll
    for (int q = 0; q < 8; ++q) {
      unsigned long long v = m8[q] & 0x0101010101010101ULL;
      unsigned long long byte = (v * 0x0102040810204080ULL) >> 56;
      r |= byte << (8 * q);
    }
  } else {  // int32 wire format
    const int* mi = (const int*)raw + (size_t)n * 64;
#pragma unroll
    for (int f = 0; f < 64; ++f)
      if (mi[f]) r |= 1ULL << f;
  }
  R[n] = r;
}

// ---- pull-mode BFS hop with saturation early-exit ----
__global__ void k_bfs_pull(const int* __restrict__ row_ptr,
                           const uint16_t* __restrict__ dst_csr,
                           const unsigned long long* __restrict__ Rold,
                           unsigned long long* __restrict__ Rnew, int N) {
  int n = blockIdx.x * blockDim.x + threadIdx.x;
  if (n >= N) return;
  unsigned long long r = Rold[n];
  if (r == ~0ULL) { Rnew[n] = r; return; }
  int s = row_ptr[n], s1 = row_ptr[n + 1];
  for (; s + 8 <= s1; s += 8) {
    int d0 = dst_csr[s], d1 = dst_csr[s+1], d2 = dst_csr[s+2], d3 = dst_csr[s+3];
    int d4 = dst_csr[s+4], d5 = dst_csr[s+5], d6 = dst_csr[s+6], d7 = dst_csr[s+7];
    unsigned long long r0 = Rold[d0] | Rold[d1];
    unsigned long long r1 = Rold[d2] | Rold[d3];
    unsigned long long r2 = Rold[d4] | Rold[d5];
    unsigned long long r3 = Rold[d6] | Rold[d7];
    r |= (r0 | r1) | (r2 | r3);
  }
  for (; s < s1; ++s) r |= Rold[dst_csr[s]];
  Rnew[n] = r;
}

// ---- dist -> pwq (split [half][N][32] bf16), z0 likewise ----
__global__ void k_distpw_z(const unsigned long long* __restrict__ R,
                           const float* __restrict__ x,
                           uint16_t* __restrict__ pwq_s, uint16_t* __restrict__ zq_s,
                           int N) {
  int wave = (blockIdx.x * blockDim.x + threadIdx.x) >> 6;
  int lane = threadIdx.x & 63;
  if (wave >= N) return;
  int d = 0;
#pragma unroll
  for (int h = 0; h < 6; ++h)
    d += (int)((~R[(size_t)h * N + wave] >> lane) & 1ULL);
  if (!((R[(size_t)6 * N + wave] >> lane) & 1ULL)) d = 0;  // unreached -> 0
  float p = c_tab[d + 5];
  int half = lane >> 5, c = lane & 31;
  size_t si = (size_t)half * N * 32 + (size_t)wave * 32 + c;
  pwq_s[si] = f2bf(p);
  bool obs = (R[wave] >> lane) & 1ULL;
  zq_s[si] = obs ? f2bf(p * x[(size_t)wave * 64 + lane]) : (uint16_t)0;
}

// ---- CSR build: count + hierarchical scan ----
__global__ void k_count(const int* __restrict__ row, int* __restrict__ cnt, int E) {
  int e = blockIdx.x * blockDim.x + threadIdx.x;
  if (e < E) atomicAdd(&cnt[row[e]], 1);
}

__global__ void k_bsum(const int* __restrict__ cnt, int* __restrict__ bsum, int N) {
  __shared__ int sm[256];
  int b = blockIdx.x, t = threadIdx.x;
  int i = b * 256 + t;
  int v = (i < N) ? cnt[i] : 0;
  sm[t] = v;
  __syncthreads();
  for (int off = 128; off > 0; off >>= 1) {
    if (t < off) sm[t] += sm[t + off];
    __syncthreads();
  }
  if (t == 0) bsum[b] = sm[0];
}

__global__ void k_bscan(const int* __restrict__ bsum, int* __restrict__ ebsum,
                        int* __restrict__ row_ptr_N, int NB) {
  __shared__ int sm[256];
  int t = threadIdx.x;
  int v = (t < NB) ? bsum[t] : 0;
  sm[t] = v;
  __syncthreads();
  for (int off = 1; off < 256; off <<= 1) {
    int tv = (t >= off) ? sm[t - off] : 0;
    __syncthreads();
    sm[t] += tv;
    __syncthreads();
  }
  if (t < NB) ebsum[t] = sm[t] - v;
  if (t == 255) *row_ptr_N = sm[255];
}

// chunk scan; also seeds bucket cursors
__global__ void k_chscan(const int* __restrict__ cnt, const int* __restrict__ ebsum,
                         int* __restrict__ row_ptr, int* __restrict__ bcur, int N) {
  __shared__ int sm[256];
  int b = blockIdx.x, t = threadIdx.x;
  int i = b * 256 + t;
  int v = (i < N) ? cnt[i] : 0;
  sm[t] = v;
  __syncthreads();
  for (int off = 1; off < 256; off <<= 1) {
    int tv = (t >= off) ? sm[t - off] : 0;
    __syncthreads();
    sm[t] += tv;
    __syncthreads();
  }
  if (i < N) {
    int ex = ebsum[b] + sm[t] - v;
    row_ptr[i] = ex;
    if (t == 0) bcur[b] = ex;
  }
}

// ---- chunked bucket scatter (2-pass, write-locality-preserving) ----
__global__ void k_bucket(const int* __restrict__ row, const int* __restrict__ col,
                         int* __restrict__ bcur, uint32_t* __restrict__ staged,
                         int E, int NBUK) {
  __shared__ int cntb[256];
  __shared__ int offb[256];
  int t = threadIdx.x;
  cntb[t] = 0;
  __syncthreads();
  int base = blockIdx.x * 4096;
#pragma unroll
  for (int k = 0; k < 16; ++k) {
    int e = base + k * 256 + t;
    if (e < E) atomicAdd(&cntb[row[e] >> 8], 1);
  }
  __syncthreads();
  {
    int c = cntb[t];
    offb[t] = (t < NBUK && c) ? atomicAdd(&bcur[t], c) : 0;
    cntb[t] = 0;
  }
  __syncthreads();
#pragma unroll
  for (int k = 0; k < 16; ++k) {
    int e = base + k * 256 + t;
    if (e < E) {
      int r = row[e], b = r >> 8;
      int pos = offb[b] + atomicAdd(&cntb[b], 1);
      staged[pos] = ((uint32_t)(r & 255) << 16) | (uint32_t)col[e];
    }
  }
}

__global__ void k_unbucket(const int* __restrict__ row_ptr,
                           const uint32_t* __restrict__ staged,
                           uint16_t* __restrict__ dst_csr, int N) {
  __shared__ int curs[256];
  int b = blockIdx.x, t = threadIdx.x;
  int nb = b * 256;
  int rlast = min(nb + 256, N);
  if (nb + t < rlast) curs[t] = row_ptr[nb + t];
  __syncthreads();
  int start = row_ptr[nb], end = row_ptr[rlast];
  for (int i = start + t; i < end; i += 256) {
    uint32_t v = staged[i];
    int pos = atomicAdd(&curs[v >> 16], 1);
    dst_csr[pos] = (uint16_t)(v & 0xFFFF);
  }
}

// ==== XCD-pinned channel-half gather family ====
// grid 2x node-blocks; half = (bid&7)>>2 pins each 32-ch half to one XCD group.
// lane = 8 channels (uint4), 4 lanes/edge-row, 16 edges/step, 2-deep unroll.

#define ACC8(v0, v1)                                              \
  a0 += bf2f(v0.x & 0xFFFF) + bf2f(v1.x & 0xFFFF);                \
  a1 += bf2f(v0.x >> 16)    + bf2f(v1.x >> 16);                   \
  a2 += bf2f(v0.y & 0xFFFF) + bf2f(v1.y & 0xFFFF);                \
  a3 += bf2f(v0.y >> 16)    + bf2f(v1.y >> 16);                   \
  a4 += bf2f(v0.z & 0xFFFF) + bf2f(v1.z & 0xFFFF);                \
  a5 += bf2f(v0.z >> 16)    + bf2f(v1.z >> 16);                   \
  a6 += bf2f(v0.w & 0xFFFF) + bf2f(v1.w & 0xFFFF);                \
  a7 += bf2f(v0.w >> 16)    + bf2f(v1.w >> 16);

#define ACC8_1(v)                                                 \
  a0 += bf2f(v.x & 0xFFFF); a1 += bf2f(v.x >> 16);                \
  a2 += bf2f(v.y & 0xFFFF); a3 += bf2f(v.y >> 16);                \
  a4 += bf2f(v.z & 0xFFFF); a5 += bf2f(v.z >> 16);                \
  a6 += bf2f(v.w & 0xFFFF); a7 += bf2f(v.w >> 16);

#define RED8S()                                                                 \
  a0 += __shfl_xor(a0, 4); a0 += __shfl_xor(a0, 8); a0 += __shfl_xor(a0, 16); a0 += __shfl_xor(a0, 32); \
  a1 += __shfl_xor(a1, 4); a1 += __shfl_xor(a1, 8); a1 += __shfl_xor(a1, 16); a1 += __shfl_xor(a1, 32); \
  a2 += __shfl_xor(a2, 4); a2 += __shfl_xor(a2, 8); a2 += __shfl_xor(a2, 16); a2 += __shfl_xor(a2, 32); \
  a3 += __shfl_xor(a3, 4); a3 += __shfl_xor(a3, 8); a3 += __shfl_xor(a3, 16); a3 += __shfl_xor(a3, 32); \
  a4 += __shfl_xor(a4, 4); a4 += __shfl_xor(a4, 8); a4 += __shfl_xor(a4, 16); a4 += __shfl_xor(a4, 32); \
  a5 += __shfl_xor(a5, 4); a5 += __shfl_xor(a5, 8); a5 += __shfl_xor(a5, 16); a5 += __shfl_xor(a5, 32); \
  a6 += __shfl_xor(a6, 4); a6 += __shfl_xor(a6, 8); a6 += __shfl_xor(a6, 16); a6 += __shfl_xor(a6, 32); \
  a7 += __shfl_xor(a7, 4); a7 += __shfl_xor(a7, 8); a7 += __shfl_xor(a7, 16); a7 += __shfl_xor(a7, 32);

#define SPLIT_HEAD(N)                                             \
  int bid = blockIdx.x;                                           \
  int half = (bid & 7) >> 2;                                      \
  int idx = (bid >> 3) * 4 + (bid & 3);                           \
  int node = idx * 4 + (int)(threadIdx.x >> 6);                   \
  if (node >= (N)) return;                                        \
  int lane = threadIdx.x & 63;                                    \
  int cq = lane & 3, g = lane >> 2;

// ---- sinv + gq over split pwq ----
__global__ void k_sinv_g(const int* __restrict__ row_ptr, const uint16_t* __restrict__ dst_csr,
                         const uint16_t* __restrict__ pwq_s, float* __restrict__ sinv,
                         uint16_t* __restrict__ gq_s, int N) {
  SPLIT_HEAD(N)
  const uint4* pw4 = (const uint4*)(pwq_s + (size_t)half * N * 32);
  uint4* gq4 = (uint4*)(gq_s + (size_t)half * N * 32);
  int base = row_ptr[node], s1 = row_ptr[node + 1];
  int nfull = (s1 - base) >> 5;
  float a0 = 0.f, a1 = 0.f, a2 = 0.f, a3 = 0.f, a4 = 0.f, a5 = 0.f, a6 = 0.f, a7 = 0.f;
  int s = base + g;
  for (int it = 0; it < nfull; ++it, s += 32) {
    int d0 = dst_csr[s], d1 = dst_csr[s + 16];
    uint4 v0 = pw4[(size_t)d0 * 4 + cq];
    uint4 v1 = pw4[(size_t)d1 * 4 + cq];
    ACC8(v0, v1)
  }
  for (s = base + (nfull << 5) + g; s < s1; s += 16) {
    uint4 v = pw4[(size_t)dst_csr[s] * 4 + cq];
    ACC8_1(v)
  }
  RED8S()
  if (g == 0) {
    float s0 = (a0 > 0.f) ? (1.f / a0) : 0.f;
    float s1f = (a1 > 0.f) ? (1.f / a1) : 0.f;
    float s2 = (a2 > 0.f) ? (1.f / a2) : 0.f;
    float s3 = (a3 > 0.f) ? (1.f / a3) : 0.f;
    float s4 = (a4 > 0.f) ? (1.f / a4) : 0.f;
    float s5 = (a5 > 0.f) ? (1.f / a5) : 0.f;
    float s6 = (a6 > 0.f) ? (1.f / a6) : 0.f;
    float s7 = (a7 > 0.f) ? (1.f / a7) : 0.f;
    size_t b64 = (size_t)node * 64 + half * 32 + (cq << 3);
    *(float4*)(sinv + b64) = make_float4(s0, s1f, s2, s3);
    *(float4*)(sinv + b64 + 4) = make_float4(s4, s5, s6, s7);
    uint4 pv = pw4[(size_t)node * 4 + cq];
    uint32_t g0 = f2bf(bf2f(pv.x & 0xFFFF) * s0);
    uint32_t g1 = f2bf(bf2f(pv.x >> 16) * s1f);
    uint32_t g2 = f2bf(bf2f(pv.y & 0xFFFF) * s2);
    uint32_t g3 = f2bf(bf2f(pv.y >> 16) * s3);
    uint32_t g4 = f2bf(bf2f(pv.z & 0xFFFF) * s4);
    uint32_t g5 = f2bf(bf2f(pv.z >> 16) * s5);
    uint32_t g6 = f2bf(bf2f(pv.w & 0xFFFF) * s6);
    uint32_t g7 = f2bf(bf2f(pv.w >> 16) * s7);
    uint4 gw;
    gw.x = g0 | (g1 << 16); gw.y = g2 | (g3 << 16);
    gw.z = g4 | (g5 << 16); gw.w = g6 | (g7 << 16);
    gq4[(size_t)node * 4 + cq] = gw;
  }
}

// ---- intermediate propagation on split bf16 z-state ----
__global__ void k_prop_q(const int* __restrict__ row_ptr, const uint16_t* __restrict__ dst_csr,
                         const uint16_t* __restrict__ gq_s,
                         const unsigned long long* __restrict__ R0,
                         const uint16_t* __restrict__ zprev_s,
                         uint16_t* __restrict__ znew_s, int N) {
  SPLIT_HEAD(N)
  const uint4* z4 = (const uint4*)(zprev_s + (size_t)half * N * 32);
  const uint4* gq4 = (const uint4*)(gq_s + (size_t)half * N * 32);
  uint4* zn4 = (uint4*)(znew_s + (size_t)half * N * 32);
  int base = row_ptr[node], s1 = row_ptr[node + 1];
  int nfull = (s1 - base) >> 5;
  float a0 = 0.f, a1 = 0.f, a2 = 0.f, a3 = 0.f, a4 = 0.f, a5 = 0.f, a6 = 0.f, a7 = 0.f;
  int s = base + g;
  for (int it = 0; it < nfull; ++it, s += 32) {
    int d0 = dst_csr[s], d1 = dst_csr[s + 16];
    uint4 v0 = z4[(size_t)d0 * 4 + cq];
    uint4 v1 = z4[(size_t)d1 * 4 + cq];
    ACC8(v0, v1)
  }
  for (s = base + (nfull << 5) + g; s < s1; s += 16) {
    uint4 v = z4[(size_t)dst_csr[s] * 4 + cq];
    ACC8_1(v)
  }
  RED8S()
  if (g == 0) {
    size_t bidx = (size_t)node * 4 + cq;
    uint4 gv = gq4[bidx];
    uint4 zp = z4[bidx];
    unsigned long long r0 = R0[node];
    int c0 = half * 32 + (cq << 3);
    uint32_t n0 = ((r0 >> c0) & 1ULL)       ? (zp.x & 0xFFFF) : (uint32_t)f2bf(bf2f(gv.x & 0xFFFF) * a0);
    uint32_t n1 = ((r0 >> (c0 + 1)) & 1ULL) ? (zp.x >> 16)    : (uint32_t)f2bf(bf2f(gv.x >> 16) * a1);
    uint32_t n2 = ((r0 >> (c0 + 2)) & 1ULL) ? (zp.y & 0xFFFF) : (uint32_t)f2bf(bf2f(gv.y & 0xFFFF) * a2);
    uint32_t n3 = ((r0 >> (c0 + 3)) & 1ULL) ? (zp.y >> 16)    : (uint32_t)f2bf(bf2f(gv.y >> 16) * a3);
    uint32_t n4 = ((r0 >> (c0 + 4)) & 1ULL) ? (zp.z & 0xFFFF) : (uint32_t)f2bf(bf2f(gv.z & 0xFFFF) * a4);
    uint32_t n5 = ((r0 >> (c0 + 5)) & 1ULL) ? (zp.z >> 16)    : (uint32_t)f2bf(bf2f(gv.z >> 16) * a5);
    uint32_t n6 = ((r0 >> (c0 + 6)) & 1ULL) ? (zp.w & 0xFFFF) : (uint32_t)f2bf(bf2f(gv.w & 0xFFFF) * a6);
    uint32_t n7 = ((r0 >> (c0 + 7)) & 1ULL) ? (zp.w >> 16)    : (uint32_t)f2bf(bf2f(gv.w >> 16) * a7);
    uint4 outw;
    outw.x = n0 | (n1 << 16); outw.y = n2 | (n3 << 16);
    outw.z = n4 | (n5 << 16); outw.w = n6 | (n7 << 16);
    zn4[bidx] = outw;
  }
}

// ---- final pass: o = obs ? x : sinv*sum (f32 into d_out, split halves) ----
__global__ void k_prop_final(const int* __restrict__ row_ptr, const uint16_t* __restrict__ dst_csr,
                             const float* __restrict__ sinv,
                             const unsigned long long* __restrict__ R0,
                             const float* __restrict__ x,
                             const uint16_t* __restrict__ zprev_s,
                             float* __restrict__ o, int N) {
  SPLIT_HEAD(N)
  const uint4* z4 = (const uint4*)(zprev_s + (size_t)half * N * 32);
  int base = row_ptr[node], s1 = row_ptr[node + 1];
  int nfull = (s1 - base) >> 5;
  float a0 = 0.f, a1 = 0.f, a2 = 0.f, a3 = 0.f, a4 = 0.f, a5 = 0.f, a6 = 0.f, a7 = 0.f;
  int s = base + g;
  for (int it = 0; it < nfull; ++it, s += 32) {
    int d0 = dst_csr[s], d1 = dst_csr[s + 16];
    uint4 v0 = z4[(size_t)d0 * 4 + cq];
    uint4 v1 = z4[(size_t)d1 * 4 + cq];
    ACC8(v0, v1)
  }
  for (s = base + (nfull << 5) + g; s < s1; s += 16) {
    uint4 v = z4[(size_t)dst_csr[s] * 4 + cq];
    ACC8_1(v)
  }
  RED8S()
  if (g == 0) {
    size_t b64 = (size_t)node * 64 + half * 32 + (cq << 3);
    float4 svA = *(const float4*)(sinv + b64);
    float4 svB = *(const float4*)(sinv + b64 + 4);
    float4 xvA = *(const float4*)(x + b64);
    float4 xvB = *(const float4*)(x + b64 + 4);
    unsigned long long r0 = R0[node];
    int c0 = half * 32 + (cq << 3);
    float o0 = ((r0 >> c0) & 1ULL)       ? xvA.x : svA.x * a0;
    float o1 = ((r0 >> (c0 + 1)) & 1ULL) ? xvA.y : svA.y * a1;
    float o2 = ((r0 >> (c0 + 2)) & 1ULL) ? xvA.z : svA.z * a2;
    float o3 = ((r0 >> (c0 + 3)) & 1ULL) ? xvA.w : svA.w * a3;
    float o4 = ((r0 >> (c0 + 4)) & 1ULL) ? xvB.x : svB.x * a4;
    float o5 = ((r0 >> (c0 + 5)) & 1ULL) ? xvB.y : svB.y * a5;
    float o6 = ((r0 >> (c0 + 6)) & 1ULL) ? xvB.z : svB.z * a6;
    float o7 = ((r0 >> (c0 + 7)) & 1ULL) ? xvB.w : svB.w * a7;
    *(float4*)(o + b64) = make_float4(o0, o1, o2, o3);
    *(float4*)(o + b64 + 4) = make_float4(o4, o5, o6, o7);
  }
}

// ---- uncentered M2 partials per block (no global atomics) ----
__global__ void k_covar(const float* __restrict__ o, float* __restrict__ Cpart,
                        float* __restrict__ mupart, int N) {
  __shared__ float yt[32][68];
  __shared__ float ms[64];
  int t = threadIdx.x, blk = blockIdx.x;
  if (t < 64) ms[t] = 0.f;
  int i0 = (t >> 4) * 4, j0 = (t & 15) * 4;
  float acc[4][4] = {};
  float csum = 0.f;
  for (size_t base = (size_t)blk * 32; base < (size_t)N;
       base += (size_t)gridDim.x * 32) {
    int rows = min(32, N - (int)base);
    for (int k = t; k < rows * 64; k += 256) {
      int nn = k >> 6, f = k & 63;
      float val = o[(base + nn) * 64 + f];
      yt[nn][f] = val;
      csum += val;
    }
    __syncthreads();
    for (int nn = 0; nn < rows; ++nn) {
      float4 a = *(const float4*)&yt[nn][i0];
      float4 b = *(const float4*)&yt[nn][j0];
      acc[0][0] += a.x * b.x; acc[0][1] += a.x * b.y; acc[0][2] += a.x * b.z; acc[0][3] += a.x * b.w;
      acc[1][0] += a.y * b.x; acc[1][1] += a.y * b.y; acc[1][2] += a.y * b.z; acc[1][3] += a.y * b.w;
      acc[2][0] += a.z * b.x; acc[2][1] += a.z * b.y; acc[2][2] += a.z * b.z; acc[2][3] += a.z * b.w;
      acc[3][0] += a.w * b.x; acc[3][1] += a.w * b.y; acc[3][2] += a.w * b.z; acc[3][3] += a.w * b.w;
    }
    __syncthreads();
  }
  float* Cb = Cpart + (size_t)blk * 4096;
#pragma unroll
  for (int a = 0; a < 4; ++a)
#pragma unroll
    for (int b = 0; b < 4; ++b)
      Cb[(size_t)(i0 + a) * 64 + j0 + b] = acc[a][b];
  atomicAdd(&ms[t & 63], csum);
  __syncthreads();
  if (t < 64) mupart[(size_t)blk * 64 + t] = ms[t];
}

__global__ void k_redC(const float* __restrict__ Cpart, float* __restrict__ M2,
                       int NBLK) {
  __shared__ float sm[16][17];
  int t = threadIdx.x;
  int li = t >> 4, part = t & 15;
  int idx = blockIdx.x * 16 + li;
  int per = NBLK >> 4;
  float s = 0.f;
  int b0 = part * per;
  for (int b = b0; b < b0 + per; ++b)
    s += Cpart[(size_t)b * 4096 + idx];
  sm[li][part] = s;
  __syncthreads();
  if (part == 0) {
    float tot = 0.f;
#pragma unroll
    for (int k = 0; k < 16; ++k) tot += sm[li][k];
    M2[idx] = tot;
  }
}

__global__ void k_redMu(const float* __restrict__ mupart, float* __restrict__ musum,
                        int NBLK) {
  int t = blockIdx.x * blockDim.x + threadIdx.x;
  int idx = t >> 4, part = t & 15;
  if (idx >= 64) return;
  int per = NBLK >> 4;
  float s = 0.f;
  int b0 = part * per;
  for (int b = b0; b < b0 + per; ++b)
    s += mupart[(size_t)b * 64 + idx];
  atomicAdd(&musum[idx], s);
}

__global__ void k_cor(const float* __restrict__ M2, const float* __restrict__ musum,
                      float* __restrict__ cor, int N) {
  int idx = blockIdx.x * blockDim.x + threadIdx.x;
  if (idx >= 4096) return;
  int i = idx >> 6, j = idx & 63;
  float inv_n = 1.f / (float)N;
  float mi = musum[i] * inv_n, mj = musum[j] * inv_n;
  float Cij = M2[idx] - (float)N * mi * mj;
  float Cii = M2[i * 64 + i] - (float)N * mi * mi;
  float Cjj = M2[j * 64 + j] - (float)N * mj * mj;
  float d = sqrtf(Cii * Cjj);
  cor[idx] = (i != j && d > 0.f) ? (Cij / d) : 0.f;
}

// ---- fusion (in place on d_out); pwq read from split layout ----
__global__ void k_fuse2(float* o, const uint16_t* __restrict__ pwq_s,
                        const float* __restrict__ musum, const float* __restrict__ cor,
                        int N) {
  __shared__ float a1t[64][65];
  __shared__ float scor[64][65];
  __shared__ float smu[64];
  int t = threadIdx.x;
  int nbase = blockIdx.x * 64;
  if (t < 64) smu[t] = musum[t] / (float)N;
#pragma unroll
  for (int j = 0; j < 16; ++j) {
    int idx = t + 256 * j;
    scor[idx >> 6][idx & 63] = cor[idx];
  }
  __syncthreads();
#pragma unroll
  for (int j = 0; j < 16; ++j) {
    int idx = t + 256 * j;
    int r = idx >> 6, c = idx & 63;
    int n = nbase + r;
    float val = 0.f;
    if (n < N) {
      size_t pidx = (size_t)(c >> 5) * N * 32 + (size_t)n * 32 + (c & 31);
      val = bf2f(pwq_s[pidx]) * (o[(size_t)n * 64 + c] - smu[c]);
    }
    a1t[r][c] = val;
  }
  __syncthreads();
  int tr = (t >> 4) * 4, tc = (t & 15) * 4;
  float acc[4][4] = {};
  for (int k = 0; k < 64; ++k) {
    float a[4], b[4];
#pragma unroll
    for (int i = 0; i < 4; ++i) a[i] = a1t[tr + i][k];
#pragma unroll
    for (int j = 0; j < 4; ++j) b[j] = scor[k][tc + j];
#pragma unroll
    for (int i = 0; i < 4; ++i)
#pragma unroll
      for (int j = 0; j < 4; ++j) acc[i][j] += a[i] * b[j];
  }
#pragma unroll
  for (int i = 0; i < 4; ++i) {
    int n = nbase + tr + i;
    if (n < N) {
#pragma unroll
      for (int j = 0; j < 4; ++j) {
        int c = tc + j;
        size_t pidx = (size_t)(c >> 5) * N * 32 + (size_t)n * 32 + (c & 31);
        float p = bf2f(pwq_s[pidx]);
        size_t gidx = (size_t)n * 64 + c;
        o[gidx] = o[gidx] + 0.5f * (1.f - p) * acc[i][j];
      }
    }
  }
}

extern "C" void kernel_launch(void* const* d_in, const int* in_sizes, int n_in,
                              void* d_out, int out_size, void* d_ws, size_t ws_size,
                              hipStream_t stream) {
  const float* x = (const float*)d_in[0];
  const int* ei = (const int*)d_in[1];
  const uint8_t* mask_raw = (const uint8_t*)d_in[2];
  int N = in_sizes[0] / 64;   // 50000 (< 65536 required for u16 CSR payload)
  int E = in_sizes[1] / 2;    // 800000
  const int* row = ei;
  const int* col = ei + E;

  char* w = (char*)d_ws;
  size_t off = 0;
  auto alloc = [&](size_t bytes) -> void* {
    void* p = w + off;
    off += (bytes + 255) & ~(size_t)255;
    return p;
  };
  unsigned long long* R = (unsigned long long*)alloc((size_t)7 * N * 8);
  int* dflag = (int*)alloc(256);
  int* cnt = (int*)alloc((size_t)N * 4);
  int* row_ptr = (int*)alloc((size_t)(N + 1) * 4);
  uint16_t* dst_csr = (uint16_t*)alloc((size_t)E * 2);
  uint32_t* staged = (uint32_t*)alloc((size_t)E * 4);
  int* bcur = (int*)alloc(256 * 4);
  int* bsum = (int*)alloc(256 * 4);
  int* ebsum = (int*)alloc(256 * 4);
  uint16_t* pwq = (uint16_t*)alloc((size_t)N * 64 * 2);   // split [2][N][32]
  float* sinv = (float*)alloc((size_t)N * 64 * 4);
  uint16_t* gq = (uint16_t*)alloc((size_t)N * 64 * 2);    // split
  uint16_t* zqA = (uint16_t*)alloc((size_t)N * 64 * 2);   // split
  uint16_t* zqB = (uint16_t*)alloc((size_t)N * 64 * 2);   // split
  const int CVB = 256;
  float* Cpart = (float*)alloc((size_t)CVB * 4096 * 4);
  float* mupart = (float*)alloc((size_t)CVB * 64 * 4);
  float* M2 = (float*)alloc(4096 * 4);
  float* musum = (float*)alloc(256);
  float* cor = (float*)alloc(4096 * 4);
  float* o = (float*)d_out;

  int gN = (N + 255) / 256;
  int gE = (E + 255) / 256;
  int total = N * 64;
  int gT = (total + 255) / 256;   // one wave per node
  int NB = (N + 255) / 256;
  int NBUK = (N + 255) / 256;     // row buckets
  int gBK = (E + 4095) / 4096;    // bucket-pass blocks
  int nodeBlocks = (N + 3) / 4;
  int gS = ((nodeBlocks * 2 + 7) / 8) * 8;  // split grid, XCD-balanced

  // 0. probe mask dtype, build hop-0 reach masks
  hipMemsetAsync(dflag, 0, 4, stream);
  k_detect<<<gT, 256, 0, stream>>>(mask_raw, total, dflag);
  k_init_masks<<<gN, 256, 0, stream>>>(mask_raw, dflag, R, N);

  // 1. CSR by row: count -> scan (seeds bcur) -> chunked bucket scatter
  hipMemsetAsync(cnt, 0, (size_t)N * 4, stream);
  k_count<<<gE, 256, 0, stream>>>(row, cnt, E);
  k_bsum<<<NB, 256, 0, stream>>>(cnt, bsum, N);
  k_bscan<<<1, 256, 0, stream>>>(bsum, ebsum, row_ptr + N, NB);
  k_chscan<<<NB, 256, 0, stream>>>(cnt, ebsum, row_ptr, bcur, N);
  k_bucket<<<gBK, 256, 0, stream>>>(row, col, bcur, staged, E, NBUK);
  k_unbucket<<<NBUK, 256, 0, stream>>>(row_ptr, staged, dst_csr, N);

  // 2. per-channel BFS, pull mode
  for (int h = 0; h < 6; ++h)
    k_bfs_pull<<<gN, 256, 0, stream>>>(row_ptr, dst_csr, R + (size_t)h * N,
                                       R + (size_t)(h + 1) * N, N);
  // 3. pwq (split bf16) and z0 in one pass
  k_distpw_z<<<gT, 256, 0, stream>>>(R, x, pwq, zqA, N);

  // 4. sinv/g (XCD-pinned channel halves)
  k_sinv_g<<<gS, 256, 0, stream>>>(row_ptr, dst_csr, pwq, sinv, gq, N);

  // 5. 7 split bf16 propagation passes + final f32 pass into d_out
  uint16_t* zsrc = zqA;
  uint16_t* zdst = zqB;
  for (int it = 0; it < 7; ++it) {
    k_prop_q<<<gS, 256, 0, stream>>>(row_ptr, dst_csr, gq, R, zsrc, zdst, N);
    uint16_t* tmp = zsrc; zsrc = zdst; zdst = tmp;
  }
  k_prop_final<<<gS, 256, 0, stream>>>(row_ptr, dst_csr, sinv, R, x, zsrc, o, N);

  // 6. correlation via per-block partials + parallel reduce
  k_covar<<<CVB, 256, 0, stream>>>(o, Cpart, mupart, N);
  hipMemsetAsync(musum, 0, 256, stream);
  k_redC<<<256, 256, 0, stream>>>(Cpart, M2, CVB);
  k_redMu<<<4, 256, 0, stream>>>(mupart, musum, CVB);
  k_cor<<<16, 256, 0, stream>>>(M2, musum, cor, N);

  // 7. fusion in place on d_out
  int gF = (N + 63) / 64;
  k_fuse2<<<gF, 256, 0, stream>>>(o, pwq, musum, cor, N);
}

// Round 13
// 421.419 us; speedup vs baseline: 1.3442x; 1.3442x over previous
//
#include <hip/hip_runtime.h>
#include <stdint.h>

// alpha^(i-5) for i=0..15 (alpha=0.9); pw = alpha^d uses c_tab[d+5]
__device__ __constant__ float c_tab[16] = {
  1.6935087808430286f, 1.5241579027587256f, 1.3717421124828532f,
  1.2345679012345678f, 1.1111111111111112f, 1.0f, 0.9f, 0.81f,
  0.729f, 0.6561f, 0.59049f, 0.531441f, 0.4782969f, 0.43046721f,
  0.387420489f, 0.3486784401f };

__device__ __forceinline__ float bf2f(uint32_t u) {  // low 16 bits = bf16
  union { unsigned int i; float f; } v; v.i = u << 16; return v.f;
}
__device__ __forceinline__ uint16_t f2bf(float f) {
  union { float f; unsigned int i; } v; v.f = f;
  unsigned r = v.i + 0x7FFFu + ((v.i >> 16) & 1u);  // RNE
  return (uint16_t)(r >> 16);
}

// ---- mask dtype probe ----
__global__ void k_detect(const uint8_t* __restrict__ m, int nbytes,
                         int* __restrict__ flag) {
  int i = blockIdx.x * blockDim.x + threadIdx.x;
  if (i < nbytes && (i & 3) && m[i]) atomicOr(flag, 1);
}

// ---- build initial 64-bit reach masks straight from the raw mask ----
__global__ void k_init_masks(const uint8_t* __restrict__ raw,
                             const int* __restrict__ flag,
                             unsigned long long* __restrict__ R, int N) {
  int n = blockIdx.x * blockDim.x + threadIdx.x;
  if (n >= N) return;
  unsigned long long r = 0;
  if (*flag) {  // u8/bool wire format
    const unsigned long long* m8 =
        (const unsigned long long*)(raw + (size_t)n * 64);
#pragma unroll
    for (int q = 0; q < 8; ++q) {
      unsigned long long v = m8[q] & 0x0101010101010101ULL;
      unsigned long long byte = (v * 0x0102040810204080ULL) >> 56;
      r |= byte << (8 * q);
    }
  } else {  // int32 wire format
    const int* mi = (const int*)raw + (size_t)n * 64;
#pragma unroll
    for (int f = 0; f < 64; ++f)
      if (mi[f]) r |= 1ULL << f;
  }
  R[n] = r;
}

// ---- pull-mode BFS hop with saturation early-exit ----
__global__ void k_bfs_pull(const int* __restrict__ row_ptr,
                           const uint16_t* __restrict__ dst_csr,
                           const unsigned long long* __restrict__ Rold,
                           unsigned long long* __restrict__ Rnew, int N) {
  int n = blockIdx.x * blockDim.x + threadIdx.x;
  if (n >= N) return;
  unsigned long long r = Rold[n];
  if (r == ~0ULL) { Rnew[n] = r; return; }
  int s = row_ptr[n], s1 = row_ptr[n + 1];
  for (; s + 8 <= s1; s += 8) {
    int d0 = dst_csr[s], d1 = dst_csr[s+1], d2 = dst_csr[s+2], d3 = dst_csr[s+3];
    int d4 = dst_csr[s+4], d5 = dst_csr[s+5], d6 = dst_csr[s+6], d7 = dst_csr[s+7];
    unsigned long long r0 = Rold[d0] | Rold[d1];
    unsigned long long r1 = Rold[d2] | Rold[d3];
    unsigned long long r2 = Rold[d4] | Rold[d5];
    unsigned long long r3 = Rold[d6] | Rold[d7];
    r |= (r0 | r1) | (r2 | r3);
  }
  for (; s < s1; ++s) r |= Rold[dst_csr[s]];
  Rnew[n] = r;
}

// ---- dist -> pwq = bf16(alpha^d), z0q = obs ? bf16(pw*x) : 0 ----
__global__ void k_distpw_z(const unsigned long long* __restrict__ R,
                           const float* __restrict__ x,
                           uint16_t* __restrict__ pwq, uint16_t* __restrict__ zq,
                           int N) {
  int wave = (blockIdx.x * blockDim.x + threadIdx.x) >> 6;
  int lane = threadIdx.x & 63;
  if (wave >= N) return;
  int d = 0;
#pragma unroll
  for (int h = 0; h < 6; ++h)
    d += (int)((~R[(size_t)h * N + wave] >> lane) & 1ULL);
  if (!((R[(size_t)6 * N + wave] >> lane) & 1ULL)) d = 0;  // unreached -> 0
  float p = c_tab[d + 5];
  size_t ni = (size_t)wave * 64 + lane;
  pwq[ni] = f2bf(p);
  bool obs = (R[wave] >> lane) & 1ULL;
  zq[ni] = obs ? f2bf(p * x[ni]) : (uint16_t)0;
}

// ---- CSR build: count + hierarchical scan ----
__global__ void k_count(const int* __restrict__ row, int* __restrict__ cnt, int E) {
  int e = blockIdx.x * blockDim.x + threadIdx.x;
  if (e < E) atomicAdd(&cnt[row[e]], 1);
}

__global__ void k_bsum(const int* __restrict__ cnt, int* __restrict__ bsum, int N) {
  __shared__ int sm[256];
  int b = blockIdx.x, t = threadIdx.x;
  int i = b * 256 + t;
  int v = (i < N) ? cnt[i] : 0;
  sm[t] = v;
  __syncthreads();
  for (int off = 128; off > 0; off >>= 1) {
    if (t < off) sm[t] += sm[t + off];
    __syncthreads();
  }
  if (t == 0) bsum[b] = sm[0];
}

__global__ void k_bscan(const int* __restrict__ bsum, int* __restrict__ ebsum,
                        int* __restrict__ row_ptr_N, int NB) {
  __shared__ int sm[256];
  int t = threadIdx.x;
  int v = (t < NB) ? bsum[t] : 0;
  sm[t] = v;
  __syncthreads();
  for (int off = 1; off < 256; off <<= 1) {
    int tv = (t >= off) ? sm[t - off] : 0;
    __syncthreads();
    sm[t] += tv;
    __syncthreads();
  }
  if (t < NB) ebsum[t] = sm[t] - v;
  if (t == 255) *row_ptr_N = sm[255];
}

// chunk scan; also seeds bucket cursors (folded k_binit)
__global__ void k_chscan(const int* __restrict__ cnt, const int* __restrict__ ebsum,
                         int* __restrict__ row_ptr, int* __restrict__ bcur, int N) {
  __shared__ int sm[256];
  int b = blockIdx.x, t = threadIdx.x;
  int i = b * 256 + t;
  int v = (i < N) ? cnt[i] : 0;
  sm[t] = v;
  __syncthreads();
  for (int off = 1; off < 256; off <<= 1) {
    int tv = (t >= off) ? sm[t - off] : 0;
    __syncthreads();
    sm[t] += tv;
    __syncthreads();
  }
  if (i < N) {
    int ex = ebsum[b] + sm[t] - v;
    row_ptr[i] = ex;
    if (t == 0) bcur[b] = ex;
  }
}

// ---- chunked bucket scatter (2-pass, write-locality-preserving) ----
__global__ void k_bucket(const int* __restrict__ row, const int* __restrict__ col,
                         int* __restrict__ bcur, uint32_t* __restrict__ staged,
                         int E, int NBUK) {
  __shared__ int cntb[256];
  __shared__ int offb[256];
  int t = threadIdx.x;
  cntb[t] = 0;
  __syncthreads();
  int base = blockIdx.x * 4096;
#pragma unroll
  for (int k = 0; k < 16; ++k) {
    int e = base + k * 256 + t;
    if (e < E) atomicAdd(&cntb[row[e] >> 8], 1);
  }
  __syncthreads();
  {
    int c = cntb[t];
    offb[t] = (t < NBUK && c) ? atomicAdd(&bcur[t], c) : 0;
    cntb[t] = 0;
  }
  __syncthreads();
#pragma unroll
  for (int k = 0; k < 16; ++k) {
    int e = base + k * 256 + t;
    if (e < E) {
      int r = row[e], b = r >> 8;
      int pos = offb[b] + atomicAdd(&cntb[b], 1);
      staged[pos] = ((uint32_t)(r & 255) << 16) | (uint32_t)col[e];
    }
  }
}

__global__ void k_unbucket(const int* __restrict__ row_ptr,
                           const uint32_t* __restrict__ staged,
                           uint16_t* __restrict__ dst_csr, int N) {
  __shared__ int curs[256];
  int b = blockIdx.x, t = threadIdx.x;
  int nb = b * 256;
  int rlast = min(nb + 256, N);
  if (nb + t < rlast) curs[t] = row_ptr[nb + t];
  __syncthreads();
  int start = row_ptr[nb], end = row_ptr[rlast];
  for (int i = start + t; i < end; i += 256) {
    uint32_t v = staged[i];
    int pos = atomicAdd(&curs[v >> 16], 1);
    dst_csr[pos] = (uint16_t)(v & 0xFFFF);
  }
}

// ==== octo-channel wide-gather family: lane = 8 channels (uint4 = bf16x8),
//      group g = lane>>3 in [0,8); wave covers 8 edges per step, 2-deep unroll ====

#define ACC8(v0, v1)                                              \
  a0 += bf2f(v0.x & 0xFFFF) + bf2f(v1.x & 0xFFFF);                \
  a1 += bf2f(v0.x >> 16)    + bf2f(v1.x >> 16);                   \
  a2 += bf2f(v0.y & 0xFFFF) + bf2f(v1.y & 0xFFFF);                \
  a3 += bf2f(v0.y >> 16)    + bf2f(v1.y >> 16);                   \
  a4 += bf2f(v0.z & 0xFFFF) + bf2f(v1.z & 0xFFFF);                \
  a5 += bf2f(v0.z >> 16)    + bf2f(v1.z >> 16);                   \
  a6 += bf2f(v0.w & 0xFFFF) + bf2f(v1.w & 0xFFFF);                \
  a7 += bf2f(v0.w >> 16)    + bf2f(v1.w >> 16);

#define ACC8_1(v)                                                 \
  a0 += bf2f(v.x & 0xFFFF); a1 += bf2f(v.x >> 16);                \
  a2 += bf2f(v.y & 0xFFFF); a3 += bf2f(v.y >> 16);                \
  a4 += bf2f(v.z & 0xFFFF); a5 += bf2f(v.z >> 16);                \
  a6 += bf2f(v.w & 0xFFFF); a7 += bf2f(v.w >> 16);

#define RED8()                                                    \
  a0 += __shfl_xor(a0, 8); a0 += __shfl_xor(a0, 16); a0 += __shfl_xor(a0, 32); \
  a1 += __shfl_xor(a1, 8); a1 += __shfl_xor(a1, 16); a1 += __shfl_xor(a1, 32); \
  a2 += __shfl_xor(a2, 8); a2 += __shfl_xor(a2, 16); a2 += __shfl_xor(a2, 32); \
  a3 += __shfl_xor(a3, 8); a3 += __shfl_xor(a3, 16); a3 += __shfl_xor(a3, 32); \
  a4 += __shfl_xor(a4, 8); a4 += __shfl_xor(a4, 16); a4 += __shfl_xor(a4, 32); \
  a5 += __shfl_xor(a5, 8); a5 += __shfl_xor(a5, 16); a5 += __shfl_xor(a5, 32); \
  a6 += __shfl_xor(a6, 8); a6 += __shfl_xor(a6, 16); a6 += __shfl_xor(a6, 32); \
  a7 += __shfl_xor(a7, 8); a7 += __shfl_xor(a7, 16); a7 += __shfl_xor(a7, 32);

// ---- sinv (f32, 2x float4 write) and gq (bf16 uint4 write) ----
__global__ void k_sinv_g(const int* __restrict__ row_ptr, const uint16_t* __restrict__ dst_csr,
                         const uint4* __restrict__ pwq4, float* __restrict__ sinv,
                         uint4* __restrict__ gq4, int N) {
  int wave = (blockIdx.x * blockDim.x + threadIdx.x) >> 6;
  int lane = threadIdx.x & 63;
  if (wave >= N) return;
  int g = lane >> 3, cq = lane & 7;
  int base = row_ptr[wave], s1 = row_ptr[wave + 1];
  int nfull = (s1 - base) >> 4;
  float a0 = 0.f, a1 = 0.f, a2 = 0.f, a3 = 0.f, a4 = 0.f, a5 = 0.f, a6 = 0.f, a7 = 0.f;
  int s = base + g;
  for (int it = 0; it < nfull; ++it, s += 16) {
    int d0 = dst_csr[s], d1 = dst_csr[s + 8];
    uint4 v0 = pwq4[(size_t)d0 * 8 + cq];
    uint4 v1 = pwq4[(size_t)d1 * 8 + cq];
    ACC8(v0, v1)
  }
  for (s = base + (nfull << 4) + g; s < s1; s += 8) {
    uint4 v = pwq4[(size_t)dst_csr[s] * 8 + cq];
    ACC8_1(v)
  }
  RED8()
  if (g == 0) {
    float s0 = (a0 > 0.f) ? (1.f / a0) : 0.f;
    float s1f = (a1 > 0.f) ? (1.f / a1) : 0.f;
    float s2 = (a2 > 0.f) ? (1.f / a2) : 0.f;
    float s3 = (a3 > 0.f) ? (1.f / a3) : 0.f;
    float s4 = (a4 > 0.f) ? (1.f / a4) : 0.f;
    float s5 = (a5 > 0.f) ? (1.f / a5) : 0.f;
    float s6 = (a6 > 0.f) ? (1.f / a6) : 0.f;
    float s7 = (a7 > 0.f) ? (1.f / a7) : 0.f;
    size_t b64 = (size_t)wave * 64 + (cq << 3);
    *(float4*)(sinv + b64) = make_float4(s0, s1f, s2, s3);
    *(float4*)(sinv + b64 + 4) = make_float4(s4, s5, s6, s7);
    uint4 pv = pwq4[(size_t)wave * 8 + cq];
    uint32_t g0 = f2bf(bf2f(pv.x & 0xFFFF) * s0);
    uint32_t g1 = f2bf(bf2f(pv.x >> 16) * s1f);
    uint32_t g2 = f2bf(bf2f(pv.y & 0xFFFF) * s2);
    uint32_t g3 = f2bf(bf2f(pv.y >> 16) * s3);
    uint32_t g4 = f2bf(bf2f(pv.z & 0xFFFF) * s4);
    uint32_t g5 = f2bf(bf2f(pv.z >> 16) * s5);
    uint32_t g6 = f2bf(bf2f(pv.w & 0xFFFF) * s6);
    uint32_t g7 = f2bf(bf2f(pv.w >> 16) * s7);
    uint4 gw;
    gw.x = g0 | (g1 << 16); gw.y = g2 | (g3 << 16);
    gw.z = g4 | (g5 << 16); gw.w = g6 | (g7 << 16);
    gq4[(size_t)wave * 8 + cq] = gw;
  }
}

// ---- intermediate propagation on bf16 z-state (uint4 gathers) ----
__global__ void k_prop_q(const int* __restrict__ row_ptr, const uint16_t* __restrict__ dst_csr,
                         const uint4* __restrict__ gq4,
                         const unsigned long long* __restrict__ R0,
                         const uint4* __restrict__ zprev4,
                         uint4* __restrict__ znew4, int N) {
  int wave = (blockIdx.x * blockDim.x + threadIdx.x) >> 6;
  int lane = threadIdx.x & 63;
  if (wave >= N) return;
  int g = lane >> 3, cq = lane & 7;
  int base = row_ptr[wave], s1 = row_ptr[wave + 1];
  int nfull = (s1 - base) >> 4;
  float a0 = 0.f, a1 = 0.f, a2 = 0.f, a3 = 0.f, a4 = 0.f, a5 = 0.f, a6 = 0.f, a7 = 0.f;
  int s = base + g;
  for (int it = 0; it < nfull; ++it, s += 16) {
    int d0 = dst_csr[s], d1 = dst_csr[s + 8];
    uint4 v0 = zprev4[(size_t)d0 * 8 + cq];
    uint4 v1 = zprev4[(size_t)d1 * 8 + cq];
    ACC8(v0, v1)
  }
  for (s = base + (nfull << 4) + g; s < s1; s += 8) {
    uint4 v = zprev4[(size_t)dst_csr[s] * 8 + cq];
    ACC8_1(v)
  }
  RED8()
  if (g == 0) {
    size_t bidx = (size_t)wave * 8 + cq;
    uint4 gv = gq4[bidx];
    uint4 zp = zprev4[bidx];
    unsigned long long r0 = R0[wave];
    int c0 = cq << 3;
    uint32_t n0 = ((r0 >> c0) & 1ULL)       ? (zp.x & 0xFFFF) : (uint32_t)f2bf(bf2f(gv.x & 0xFFFF) * a0);
    uint32_t n1 = ((r0 >> (c0 + 1)) & 1ULL) ? (zp.x >> 16)    : (uint32_t)f2bf(bf2f(gv.x >> 16) * a1);
    uint32_t n2 = ((r0 >> (c0 + 2)) & 1ULL) ? (zp.y & 0xFFFF) : (uint32_t)f2bf(bf2f(gv.y & 0xFFFF) * a2);
    uint32_t n3 = ((r0 >> (c0 + 3)) & 1ULL) ? (zp.y >> 16)    : (uint32_t)f2bf(bf2f(gv.y >> 16) * a3);
    uint32_t n4 = ((r0 >> (c0 + 4)) & 1ULL) ? (zp.z & 0xFFFF) : (uint32_t)f2bf(bf2f(gv.z & 0xFFFF) * a4);
    uint32_t n5 = ((r0 >> (c0 + 5)) & 1ULL) ? (zp.z >> 16)    : (uint32_t)f2bf(bf2f(gv.z >> 16) * a5);
    uint32_t n6 = ((r0 >> (c0 + 6)) & 1ULL) ? (zp.w & 0xFFFF) : (uint32_t)f2bf(bf2f(gv.w & 0xFFFF) * a6);
    uint32_t n7 = ((r0 >> (c0 + 7)) & 1ULL) ? (zp.w >> 16)    : (uint32_t)f2bf(bf2f(gv.w >> 16) * a7);
    uint4 outw;
    outw.x = n0 | (n1 << 16); outw.y = n2 | (n3 << 16);
    outw.z = n4 | (n5 << 16); outw.w = n6 | (n7 << 16);
    znew4[bidx] = outw;
  }
}

// ---- final pass: o = obs ? x : sinv*sum (f32, 2x float4 write into d_out) ----
__global__ void k_prop_final(const int* __restrict__ row_ptr, const uint16_t* __restrict__ dst_csr,
                             const float* __restrict__ sinv,
                             const unsigned long long* __restrict__ R0,
                             const float* __restrict__ x,
                             const uint4* __restrict__ zprev4,
                             float* __restrict__ o, int N) {
  int wave = (blockIdx.x * blockDim.x + threadIdx.x) >> 6;
  int lane = threadIdx.x & 63;
  if (wave >= N) return;
  int g = lane >> 3, cq = lane & 7;
  int base = row_ptr[wave], s1 = row_ptr[wave + 1];
  int nfull = (s1 - base) >> 4;
  float a0 = 0.f, a1 = 0.f, a2 = 0.f, a3 = 0.f, a4 = 0.f, a5 = 0.f, a6 = 0.f, a7 = 0.f;
  int s = base + g;
  for (int it = 0; it < nfull; ++it, s += 16) {
    int d0 = dst_csr[s], d1 = dst_csr[s + 8];
    uint4 v0 = zprev4[(size_t)d0 * 8 + cq];
    uint4 v1 = zprev4[(size_t)d1 * 8 + cq];
    ACC8(v0, v1)
  }
  for (s = base + (nfull << 4) + g; s < s1; s += 8) {
    uint4 v = zprev4[(size_t)dst_csr[s] * 8 + cq];
    ACC8_1(v)
  }
  RED8()
  if (g == 0) {
    size_t b64 = (size_t)wave * 64 + (cq << 3);
    float4 svA = *(const float4*)(sinv + b64);
    float4 svB = *(const float4*)(sinv + b64 + 4);
    float4 xvA = *(const float4*)(x + b64);
    float4 xvB = *(const float4*)(x + b64 + 4);
    unsigned long long r0 = R0[wave];
    int c0 = cq << 3;
    float o0 = ((r0 >> c0) & 1ULL)       ? xvA.x : svA.x * a0;
    float o1 = ((r0 >> (c0 + 1)) & 1ULL) ? xvA.y : svA.y * a1;
    float o2 = ((r0 >> (c0 + 2)) & 1ULL) ? xvA.z : svA.z * a2;
    float o3 = ((r0 >> (c0 + 3)) & 1ULL) ? xvA.w : svA.w * a3;
    float o4 = ((r0 >> (c0 + 4)) & 1ULL) ? xvB.x : svB.x * a4;
    float o5 = ((r0 >> (c0 + 5)) & 1ULL) ? xvB.y : svB.y * a5;
    float o6 = ((r0 >> (c0 + 6)) & 1ULL) ? xvB.z : svB.z * a6;
    float o7 = ((r0 >> (c0 + 7)) & 1ULL) ? xvB.w : svB.w * a7;
    *(float4*)(o + b64) = make_float4(o0, o1, o2, o3);
    *(float4*)(o + b64 + 4) = make_float4(o4, o5, o6, o7);
  }
}

// ---- uncentered M2 partials per block (no global atomics) ----
__global__ void k_covar(const float* __restrict__ o, float* __restrict__ Cpart,
                        float* __restrict__ mupart, int N) {
  __shared__ float yt[32][68];
  __shared__ float ms[64];
  int t = threadIdx.x, blk = blockIdx.x;
  if (t < 64) ms[t] = 0.f;
  int i0 = (t >> 4) * 4, j0 = (t & 15) * 4;
  float acc[4][4] = {};
  float csum = 0.f;
  for (size_t base = (size_t)blk * 32; base < (size_t)N;
       base += (size_t)gridDim.x * 32) {
    int rows = min(32, N - (int)base);
    for (int k = t; k < rows * 64; k += 256) {
      int nn = k >> 6, f = k & 63;
      float val = o[(base + nn) * 64 + f];
      yt[nn][f] = val;
      csum += val;
    }
    __syncthreads();
    for (int nn = 0; nn < rows; ++nn) {
      float4 a = *(const float4*)&yt[nn][i0];
      float4 b = *(const float4*)&yt[nn][j0];
      acc[0][0] += a.x * b.x; acc[0][1] += a.x * b.y; acc[0][2] += a.x * b.z; acc[0][3] += a.x * b.w;
      acc[1][0] += a.y * b.x; acc[1][1] += a.y * b.y; acc[1][2] += a.y * b.z; acc[1][3] += a.y * b.w;
      acc[2][0] += a.z * b.x; acc[2][1] += a.z * b.y; acc[2][2] += a.z * b.z; acc[2][3] += a.z * b.w;
      acc[3][0] += a.w * b.x; acc[3][1] += a.w * b.y; acc[3][2] += a.w * b.z; acc[3][3] += a.w * b.w;
    }
    __syncthreads();
  }
  float* Cb = Cpart + (size_t)blk * 4096;
#pragma unroll
  for (int a = 0; a < 4; ++a)
#pragma unroll
    for (int b = 0; b < 4; ++b)
      Cb[(size_t)(i0 + a) * 64 + j0 + b] = acc[a][b];
  atomicAdd(&ms[t & 63], csum);
  __syncthreads();
  if (t < 64) mupart[(size_t)blk * 64 + t] = ms[t];
}

__global__ void k_redC(const float* __restrict__ Cpart, float* __restrict__ M2,
                       int NBLK) {
  __shared__ float sm[16][17];
  int t = threadIdx.x;
  int li = t >> 4, part = t & 15;
  int idx = blockIdx.x * 16 + li;
  int per = NBLK >> 4;
  float s = 0.f;
  int b0 = part * per;
  for (int b = b0; b < b0 + per; ++b)
    s += Cpart[(size_t)b * 4096 + idx];
  sm[li][part] = s;
  __syncthreads();
  if (part == 0) {
    float tot = 0.f;
#pragma unroll
    for (int k = 0; k < 16; ++k) tot += sm[li][k];
    M2[idx] = tot;
  }
}

__global__ void k_redMu(const float* __restrict__ mupart, float* __restrict__ musum,
                        int NBLK) {
  int t = blockIdx.x * blockDim.x + threadIdx.x;
  int idx = t >> 4, part = t & 15;
  if (idx >= 64) return;
  int per = NBLK >> 4;
  float s = 0.f;
  int b0 = part * per;
  for (int b = b0; b < b0 + per; ++b)
    s += mupart[(size_t)b * 64 + idx];
  atomicAdd(&musum[idx], s);
}

__global__ void k_cor(const float* __restrict__ M2, const float* __restrict__ musum,
                      float* __restrict__ cor, int N) {
  int idx = blockIdx.x * blockDim.x + threadIdx.x;
  if (idx >= 4096) return;
  int i = idx >> 6, j = idx & 63;
  float inv_n = 1.f / (float)N;
  float mi = musum[i] * inv_n, mj = musum[j] * inv_n;
  float Cij = M2[idx] - (float)N * mi * mj;
  float Cii = M2[i * 64 + i] - (float)N * mi * mi;
  float Cjj = M2[j * 64 + j] - (float)N * mj * mj;
  float d = sqrtf(Cii * Cjj);
  cor[idx] = (i != j && d > 0.f) ? (Cij / d) : 0.f;
}

// ---- fusion (in place on d_out): out = o + 0.5*(1-p)*((p*(o-mu)) @ cor) ----
__global__ void k_fuse2(float* o, const uint16_t* __restrict__ pwq,
                        const float* __restrict__ musum, const float* __restrict__ cor,
                        int N) {
  __shared__ float a1t[64][65];
  __shared__ float scor[64][65];
  __shared__ float smu[64];
  int t = threadIdx.x;
  int nbase = blockIdx.x * 64;
  if (t < 64) smu[t] = musum[t] / (float)N;
#pragma unroll
  for (int j = 0; j < 16; ++j) {
    int idx = t + 256 * j;
    scor[idx >> 6][idx & 63] = cor[idx];
  }
  __syncthreads();
#pragma unroll
  for (int j = 0; j < 16; ++j) {
    int idx = t + 256 * j;
    int r = idx >> 6, c = idx & 63;
    int n = nbase + r;
    float val = 0.f;
    if (n < N) {
      size_t gidx = (size_t)n * 64 + c;
      val = bf2f(pwq[gidx]) * (o[gidx] - smu[c]);
    }
    a1t[r][c] = val;
  }
  __syncthreads();
  int tr = (t >> 4) * 4, tc = (t & 15) * 4;
  float acc[4][4] = {};
  for (int k = 0; k < 64; ++k) {
    float a[4], b[4];
#pragma unroll
    for (int i = 0; i < 4; ++i) a[i] = a1t[tr + i][k];
#pragma unroll
    for (int j = 0; j < 4; ++j) b[j] = scor[k][tc + j];
#pragma unroll
    for (int i = 0; i < 4; ++i)
#pragma unroll
      for (int j = 0; j < 4; ++j) acc[i][j] += a[i] * b[j];
  }
#pragma unroll
  for (int i = 0; i < 4; ++i) {
    int n = nbase + tr + i;
    if (n < N) {
#pragma unroll
      for (int j = 0; j < 4; ++j) {
        size_t gidx = (size_t)n * 64 + tc + j;
        float p = bf2f(pwq[gidx]);
        o[gidx] = o[gidx] + 0.5f * (1.f - p) * acc[i][j];
      }
    }
  }
}

extern "C" void kernel_launch(void* const* d_in, const int* in_sizes, int n_in,
                              void* d_out, int out_size, void* d_ws, size_t ws_size,
                              hipStream_t stream) {
  const float* x = (const float*)d_in[0];
  const int* ei = (const int*)d_in[1];
  const uint8_t* mask_raw = (const uint8_t*)d_in[2];
  int N = in_sizes[0] / 64;   // 50000 (< 65536 required for u16 CSR payload)
  int E = in_sizes[1] / 2;    // 800000
  const int* row = ei;
  const int* col = ei + E;

  char* w = (char*)d_ws;
  size_t off = 0;
  auto alloc = [&](size_t bytes) -> void* {
    void* p = w + off;
    off += (bytes + 255) & ~(size_t)255;
    return p;
  };
  unsigned long long* R = (unsigned long long*)alloc((size_t)7 * N * 8);
  int* dflag = (int*)alloc(256);
  int* cnt = (int*)alloc((size_t)N * 4);
  int* row_ptr = (int*)alloc((size_t)(N + 1) * 4);
  uint16_t* dst_csr = (uint16_t*)alloc((size_t)E * 2);
  uint32_t* staged = (uint32_t*)alloc((size_t)E * 4);
  int* bcur = (int*)alloc(256 * 4);
  int* bsum = (int*)alloc(256 * 4);
  int* ebsum = (int*)alloc(256 * 4);
  uint16_t* pwq = (uint16_t*)alloc((size_t)N * 64 * 2);
  float* sinv = (float*)alloc((size_t)N * 64 * 4);
  uint16_t* gq = (uint16_t*)alloc((size_t)N * 64 * 2);
  uint16_t* zqA = (uint16_t*)alloc((size_t)N * 64 * 2);
  uint16_t* zqB = (uint16_t*)alloc((size_t)N * 64 * 2);
  const int CVB = 256;
  float* Cpart = (float*)alloc((size_t)CVB * 4096 * 4);
  float* mupart = (float*)alloc((size_t)CVB * 64 * 4);
  float* M2 = (float*)alloc(4096 * 4);
  float* musum = (float*)alloc(256);
  float* cor = (float*)alloc(4096 * 4);
  float* o = (float*)d_out;

  int gN = (N + 255) / 256;
  int gE = (E + 255) / 256;
  int total = N * 64;
  int gT = (total + 255) / 256;  // one wave per node
  int NB = (N + 255) / 256;
  int NBUK = (N + 255) / 256;    // 196 row buckets
  int gBK = (E + 4095) / 4096;   // bucket-pass blocks

  // 0. probe mask dtype, build hop-0 reach masks
  hipMemsetAsync(dflag, 0, 4, stream);
  k_detect<<<gT, 256, 0, stream>>>(mask_raw, total, dflag);
  k_init_masks<<<gN, 256, 0, stream>>>(mask_raw, dflag, R, N);

  // 1. CSR by row: count -> scan (seeds bcur) -> chunked bucket scatter
  hipMemsetAsync(cnt, 0, (size_t)N * 4, stream);
  k_count<<<gE, 256, 0, stream>>>(row, cnt, E);
  k_bsum<<<NB, 256, 0, stream>>>(cnt, bsum, N);
  k_bscan<<<1, 256, 0, stream>>>(bsum, ebsum, row_ptr + N, NB);
  k_chscan<<<NB, 256, 0, stream>>>(cnt, ebsum, row_ptr, bcur, N);
  k_bucket<<<gBK, 256, 0, stream>>>(row, col, bcur, staged, E, NBUK);
  k_unbucket<<<NBUK, 256, 0, stream>>>(row_ptr, staged, dst_csr, N);

  // 2. per-channel BFS, pull mode
  for (int h = 0; h < 6; ++h)
    k_bfs_pull<<<gN, 256, 0, stream>>>(row_ptr, dst_csr, R + (size_t)h * N,
                                       R + (size_t)(h + 1) * N, N);
  // 3. pwq (bf16) and z0 (bf16) in one pass
  k_distpw_z<<<gT, 256, 0, stream>>>(R, x, pwq, zqA, N);

  // 4. sinv/g (octo-channel uint4 gathers)
  k_sinv_g<<<gT, 256, 0, stream>>>(row_ptr, dst_csr, (const uint4*)pwq, sinv,
                                   (uint4*)gq, N);

  // 5. 7 uint4-gather bf16 propagation passes + final f32 pass into d_out
  uint16_t* zsrc = zqA;
  uint16_t* zdst = zqB;
  for (int it = 0; it < 7; ++it) {
    k_prop_q<<<gT, 256, 0, stream>>>(row_ptr, dst_csr, (const uint4*)gq, R,
                                     (const uint4*)zsrc, (uint4*)zdst, N);
    uint16_t* tmp = zsrc; zsrc = zdst; zdst = tmp;
  }
  k_prop_final<<<gT, 256, 0, stream>>>(row_ptr, dst_csr, sinv, R, x,
                                       (const uint4*)zsrc, o, N);

  // 6. correlation via per-block partials + parallel reduce
  k_covar<<<CVB, 256, 0, stream>>>(o, Cpart, mupart, N);
  hipMemsetAsync(musum, 0, 256, stream);
  k_redC<<<256, 256, 0, stream>>>(Cpart, M2, CVB);
  k_redMu<<<4, 256, 0, stream>>>(mupart, musum, CVB);
  k_cor<<<16, 256, 0, stream>>>(M2, musum, cor, N);

  // 7. fusion in place on d_out
  int gF = (N + 63) / 64;
  k_fuse2<<<gF, 256, 0, stream>>>(o, pwq, musum, cor, N);
}